// Round 1
// baseline (179.497 us; speedup 1.0000x reference)
//
#include <hip/hip_runtime.h>
#include <math.h>

// Problem dims
#define BB 2048
#define CC 64
#define BERT 768
#define N_CTRY 250
#define N_CODES 654

// ws layout (floats)
#define OFF_PCHAT   0                    // [250][24] normalized country projections
#define OFF_CODEHAT (250*24)             // [654][8]  normalized code embeddings
#define OFF_XALL    (OFF_CODEHAT + 654*8)// [2048][80]: 0-23 x̂, 24-31 x̂code, 32-55 x̂other, 56-79 x̂doc

// ---------------------------------------------------------------------------
// Kernel 1: precompute normalized country projections + normalized code rows
// blocks 0..249: one block per country row. blocks 250..252: code rows.
// ---------------------------------------------------------------------------
__global__ __launch_bounds__(256) void k1_precompute(
    const float* __restrict__ ctab,   // [250][768]
    const float* __restrict__ W_cet,  // [24][768]
    const float* __restrict__ b_cet,  // [24]
    const float* __restrict__ code_emb, // [654][8]
    float* __restrict__ ws) {
  float* pchat   = ws + OFF_PCHAT;
  float* codehat = ws + OFF_CODEHAT;
  const int bid = blockIdx.x;
  const int tid = threadIdx.x;
  if (bid < N_CTRY) {
    __shared__ float s_proj[24];
    __shared__ float s_inv;
    const int w = tid >> 6, lane = tid & 63;
    const float4* in4 = (const float4*)(ctab + bid * BERT);
    // 24 outputs / 4 waves = 6 per wave
    for (int jj = 0; jj < 6; ++jj) {
      const int j = w * 6 + jj;
      const float4* w4p = (const float4*)(W_cet + j * BERT);
      float acc = 0.f;
#pragma unroll
      for (int i = 0; i < 3; ++i) {
        float4 a = in4[lane + 64 * i];
        float4 wv = w4p[lane + 64 * i];
        acc += a.x * wv.x + a.y * wv.y + a.z * wv.z + a.w * wv.w;
      }
#pragma unroll
      for (int m = 32; m >= 1; m >>= 1) acc += __shfl_xor(acc, m, 64);
      if (lane == 0) s_proj[j] = acc + b_cet[j];
    }
    __syncthreads();
    if (tid == 0) {
      float ss = 0.f;
      for (int k = 0; k < 24; ++k) ss += s_proj[k] * s_proj[k];
      s_inv = 1.f / fmaxf(sqrtf(ss), 1e-8f);
    }
    __syncthreads();
    if (tid < 24) pchat[bid * 24 + tid] = s_proj[tid] * s_inv;
  } else {
    const int idx = (bid - N_CTRY) * 256 + tid;
    if (idx < N_CODES) {
      float v[8];
      float ss = 0.f;
#pragma unroll
      for (int k = 0; k < 8; ++k) { v[k] = code_emb[idx * 8 + k]; ss += v[k] * v[k]; }
      const float inv = 1.f / fmaxf(sqrtf(ss), 1e-8f);
#pragma unroll
      for (int k = 0; k < 8; ++k) codehat[idx * 8 + k] = v[k] * inv;
    }
  }
}

// ---------------------------------------------------------------------------
// Kernel 2: per-row projections, normalized. 4 rows/block, 256 threads.
// Wave w computes outputs j = 20w .. 20w+19 for all 4 rows.
//  j<24:  W_t2c[j]   · placename  (+b_t2c)   group 0
//  j<32:  W_code[j-24]· placename (+b_code)  group 1
//  j<56:  W_ctx[j-32]· other_locs (+b_ctx)   group 2
//  j<80:  W_ctx[j-56]· doc        (+b_ctx)   group 3
// ---------------------------------------------------------------------------
__global__ __launch_bounds__(256) void k2_project(
    const float* __restrict__ place, const float* __restrict__ other,
    const float* __restrict__ doc,
    const float* __restrict__ W_t2c, const float* __restrict__ b_t2c,
    const float* __restrict__ W_code, const float* __restrict__ b_code,
    const float* __restrict__ W_ctx, const float* __restrict__ b_ctx,
    float* __restrict__ ws) {
  float* xall = ws + OFF_XALL;
  __shared__ float s_out[4][80];
  __shared__ float s_inv[4][4];
  const int tid = threadIdx.x;
  const int w = tid >> 6, lane = tid & 63;
  const int row0 = blockIdx.x * 4;

  for (int jj = 0; jj < 20; ++jj) {
    const int j = w * 20 + jj;
    const float* wrow;
    const float* inbase;
    float bias;
    if (j < 24)      { wrow = W_t2c + j * BERT;        inbase = place; bias = b_t2c[j]; }
    else if (j < 32) { wrow = W_code + (j - 24) * BERT; inbase = place; bias = b_code[j - 24]; }
    else if (j < 56) { wrow = W_ctx + (j - 32) * BERT;  inbase = other; bias = b_ctx[j - 32]; }
    else             { wrow = W_ctx + (j - 56) * BERT;  inbase = doc;   bias = b_ctx[j - 56]; }
    const float4* w4p = (const float4*)wrow;
    float acc[4] = {0.f, 0.f, 0.f, 0.f};
#pragma unroll
    for (int i = 0; i < 3; ++i) {
      const int idx = lane + 64 * i;
      float4 wv = w4p[idx];
#pragma unroll
      for (int r = 0; r < 4; ++r) {
        const float4* a4 = (const float4*)(inbase + (size_t)(row0 + r) * BERT);
        float4 a = a4[idx];
        acc[r] += a.x * wv.x + a.y * wv.y + a.z * wv.z + a.w * wv.w;
      }
    }
#pragma unroll
    for (int m = 32; m >= 1; m >>= 1) {
#pragma unroll
      for (int r = 0; r < 4; ++r) acc[r] += __shfl_xor(acc[r], m, 64);
    }
    if (lane == 0) {
#pragma unroll
      for (int r = 0; r < 4; ++r) s_out[r][j] = acc[r] + bias;
    }
  }
  __syncthreads();
  if (tid < 16) {
    const int r = tid >> 2, g = tid & 3;
    const int st[5] = {0, 24, 32, 56, 80};
    float ss = 0.f;
    for (int k = st[g]; k < st[g + 1]; ++k) ss += s_out[r][k] * s_out[r][k];
    s_inv[r][g] = 1.f / fmaxf(sqrtf(ss), 1e-8f);
  }
  __syncthreads();
  for (int base = tid; base < 320; base += 256) {
    const int r = base / 80, j = base % 80;
    const int g = (j < 24) ? 0 : (j < 32) ? 1 : (j < 56) ? 2 : 3;
    xall[(size_t)(row0 + r) * 80 + j] = s_out[r][j] * s_inv[r][g];
  }
}

// ---------------------------------------------------------------------------
// Kernel 3: per-(b,c) classify. 256 threads = 4 waves = 4 rows; lane = class.
// C = 64 == wave size, so softmax is one wave butterfly.
// ---------------------------------------------------------------------------
__global__ __launch_bounds__(256) void k3_classify(
    const int* __restrict__ fcodes, const int* __restrict__ ccodes,
    const float* __restrict__ gaz,
    const float* __restrict__ W_mix1, const float* __restrict__ b_mix1,
    const float* __restrict__ W_mix2, const float* __restrict__ b_mix2,
    const float* __restrict__ W_last, const float* __restrict__ b_last,
    const float* __restrict__ ws, float* __restrict__ out) {
  const float* pchat   = ws + OFF_PCHAT;
  const float* codehat = ws + OFF_CODEHAT;
  const float* xall    = ws + OFF_XALL;
  const int tid = threadIdx.x;
  const int w = tid >> 6, lane = tid & 63;
  const int row = __builtin_amdgcn_readfirstlane(blockIdx.x * 4 + w);
  const float* xv = xall + (size_t)row * 80;

  const int cidx = ccodes[row * CC + lane];
  const int fidx = fcodes[row * CC + lane];

  float cc[24];
  {
    const float4* p4 = (const float4*)(pchat + cidx * 24);
#pragma unroll
    for (int i = 0; i < 6; ++i) {
      float4 v = p4[i];
      cc[4 * i + 0] = v.x; cc[4 * i + 1] = v.y; cc[4 * i + 2] = v.z; cc[4 * i + 3] = v.w;
    }
  }
  float cd[8];
  {
    const float4* q4 = (const float4*)(codehat + fidx * 8);
#pragma unroll
    for (int i = 0; i < 2; ++i) {
      float4 v = q4[i];
      cd[4 * i + 0] = v.x; cd[4 * i + 1] = v.y; cd[4 * i + 2] = v.z; cd[4 * i + 3] = v.w;
    }
  }

  float sc = 0.f, so = 0.f, sd = 0.f, sq = 0.f;
#pragma unroll
  for (int k = 0; k < 24; ++k) {
    sc += xv[k] * cc[k];
    so += xv[32 + k] * cc[k];
    sd += xv[56 + k] * cc[k];
  }
#pragma unroll
  for (int k = 0; k < 8; ++k) sq += xv[24 + k] * cd[k];

  float f[13];
  f[0] = sc; f[1] = sq; f[2] = so; f[3] = sd;
  {
    const float* g = gaz + (size_t)(row * CC + lane) * 9;
#pragma unroll
    for (int i = 0; i < 9; ++i) f[4 + i] = g[i];
  }

  float h1[24];
#pragma unroll
  for (int j = 0; j < 24; ++j) {
    float a = b_mix1[j];
#pragma unroll
    for (int i = 0; i < 13; ++i) a += W_mix1[j * 13 + i] * f[i];
    h1[j] = 1.f / (1.f + __expf(-a));
  }
  float h2[24];
#pragma unroll
  for (int j = 0; j < 24; ++j) {
    float a = b_mix2[j];
#pragma unroll
    for (int i = 0; i < 24; ++i) a += W_mix2[j * 24 + i] * h1[i];
    h2[j] = 1.f / (1.f + __expf(-a));
  }
  float last = b_last[0];
#pragma unroll
  for (int k = 0; k < 24; ++k) last += W_last[k] * h2[k];

  // softmax across the 64 lanes (classes)
  float m = last;
#pragma unroll
  for (int s = 32; s >= 1; s >>= 1) m = fmaxf(m, __shfl_xor(m, s, 64));
  const float e = __expf(last - m);
  float ssum = e;
#pragma unroll
  for (int s = 32; s >= 1; s >>= 1) ssum += __shfl_xor(ssum, s, 64);
  out[row * CC + lane] = e / ssum;
}

// ---------------------------------------------------------------------------
extern "C" void kernel_launch(void* const* d_in, const int* in_sizes, int n_in,
                              void* d_out, int out_size, void* d_ws, size_t ws_size,
                              hipStream_t stream) {
  const float* place   = (const float*)d_in[0];
  const float* other   = (const float*)d_in[1];
  const float* doc     = (const float*)d_in[2];
  const int*   fcodes  = (const int*)d_in[3];
  const int*   ccodes  = (const int*)d_in[4];
  const float* gaz     = (const float*)d_in[5];
  const float* code_emb= (const float*)d_in[6];
  const float* ctab    = (const float*)d_in[7];
  const float* W_cet   = (const float*)d_in[8];
  const float* b_cet   = (const float*)d_in[9];
  const float* W_t2c   = (const float*)d_in[10];
  const float* b_t2c   = (const float*)d_in[11];
  const float* W_ctx   = (const float*)d_in[12];
  const float* b_ctx   = (const float*)d_in[13];
  const float* W_code  = (const float*)d_in[14];
  const float* b_code  = (const float*)d_in[15];
  const float* W_mix1  = (const float*)d_in[16];
  const float* b_mix1  = (const float*)d_in[17];
  const float* W_mix2  = (const float*)d_in[18];
  const float* b_mix2  = (const float*)d_in[19];
  const float* W_last  = (const float*)d_in[20];
  const float* b_last  = (const float*)d_in[21];
  float* ws  = (float*)d_ws;
  float* out = (float*)d_out;

  // k1: 250 country blocks + 3 blocks for 654 code rows
  k1_precompute<<<N_CTRY + 3, 256, 0, stream>>>(ctab, W_cet, b_cet, code_emb, ws);
  // k2: 2048 rows / 4 rows per block
  k2_project<<<BB / 4, 256, 0, stream>>>(place, other, doc, W_t2c, b_t2c,
                                         W_code, b_code, W_ctx, b_ctx, ws);
  // k3: 2048 rows / 4 rows per block
  k3_classify<<<BB / 4, 256, 0, stream>>>(fcodes, ccodes, gaz, W_mix1, b_mix1,
                                          W_mix2, b_mix2, W_last, b_last, ws, out);
}

// Round 2
// 172.521 us; speedup vs baseline: 1.0404x; 1.0404x over previous
//
#include <hip/hip_runtime.h>
#include <math.h>

// Problem dims
#define BB 2048
#define CC 64
#define BERT 768
#define N_CTRY 250
#define N_CODES 654

// ws layout (floats)
#define OFF_PCHAT   0                    // [250][24] normalized country projections
#define OFF_CODEHAT (250*24)             // [654][8]  normalized code embeddings
#define OFF_XALL    (OFF_CODEHAT + 654*8)// [2048][80]: 0-23 x̂, 24-31 x̂code, 32-55 x̂other, 56-79 x̂doc

// ---------------------------------------------------------------------------
// Fused kernel A:
//   blocks [0, 512)    : per-row projections (4 rows/block), normalized -> xall
//   blocks [512, 762)  : country-table projection (1 row/block), normalized -> pchat
//   blocks [762, 765)  : code-embedding normalization -> codehat
//
// Projection path design (the former 62 us hot spot):
//   - stage 4 rows x 3 tensors in LDS once (36 KB, stride-1 = conflict-free)
//   - wave w owns outputs j in [20w, 20w+20), processed in groups of 4
//     (group boundaries 24/32/56 are all multiples of 4 -> one tensor/group)
//   - weights for the 4 j's held in registers; each LDS float4 read feeds
//     16 FMAs (4 j x 4 elems); accumulators acc[4 rows][20 j] stay in VGPRs
//   - ONE deferred 6-stage butterfly over all 80 accumulators at the end
//     (independent chains -> throughput-bound, not latency-bound)
// ---------------------------------------------------------------------------
__global__ __launch_bounds__(256, 2) void kA_fused(
    const float* __restrict__ place, const float* __restrict__ other,
    const float* __restrict__ doc,
    const float* __restrict__ W_t2c, const float* __restrict__ b_t2c,
    const float* __restrict__ W_code, const float* __restrict__ b_code,
    const float* __restrict__ W_ctx, const float* __restrict__ b_ctx,
    const float* __restrict__ ctab, const float* __restrict__ W_cet,
    const float* __restrict__ b_cet, const float* __restrict__ code_emb,
    float* __restrict__ ws) {
  __shared__ float s_in[12][768];    // [tensor*4 + r][k]   36 KB
  __shared__ float s_proj[4][80];
  __shared__ float s_inv2[4][4];

  const int bid = blockIdx.x;
  const int tid = threadIdx.x;
  const int w = tid >> 6, lane = tid & 63;

  if (bid < 512) {
    // ---------------- per-row projection path ----------------
    float* xall = ws + OFF_XALL;
    const int row0 = bid * 4;

    // stage 12 input rows into LDS, coalesced
    for (int f = tid; f < 2304; f += 256) {   // 2304 float4 = 12*768 floats
      const int rowi = f / 192;               // 0..11
      const int col4 = f % 192;
      const int t = rowi >> 2, r = rowi & 3;
      const float* bp = (t == 0) ? place : (t == 1) ? other : doc;
      float4 v = ((const float4*)(bp + (size_t)(row0 + r) * BERT))[col4];
      reinterpret_cast<float4*>(&s_in[0][0])[f] = v;
    }
    __syncthreads();

    float acc[4][20];
#pragma unroll
    for (int r = 0; r < 4; ++r)
#pragma unroll
      for (int jj = 0; jj < 20; ++jj) acc[r][jj] = 0.f;

    const int j0w = w * 20;
#pragma unroll
    for (int g = 0; g < 5; ++g) {
      const int j0 = j0w + g * 4;             // wave-uniform
      const float* wbase;
      int jb;
      if (j0 < 24)      { wbase = W_t2c;  jb = j0; }
      else if (j0 < 32) { wbase = W_code; jb = j0 - 24; }
      else if (j0 < 56) { wbase = W_ctx;  jb = j0 - 32; }
      else              { wbase = W_ctx;  jb = j0 - 56; }
      const int t = (j0 < 32) ? 0 : (j0 < 56) ? 1 : 2;

      // hoist 4 weight rows (this wave's j group) into registers
      float4 wv[4][3];
#pragma unroll
      for (int u = 0; u < 4; ++u) {
        const float4* wr = (const float4*)(wbase + (size_t)(jb + u) * BERT);
#pragma unroll
        for (int i = 0; i < 3; ++i) wv[u][i] = wr[lane + 64 * i];
      }
#pragma unroll
      for (int i = 0; i < 3; ++i) {
#pragma unroll
        for (int r = 0; r < 4; ++r) {
          float4 a = reinterpret_cast<const float4*>(&s_in[t * 4 + r][0])[lane + 64 * i];
#pragma unroll
          for (int u = 0; u < 4; ++u) {
            acc[r][g * 4 + u] += a.x * wv[u][i].x + a.y * wv[u][i].y +
                                 a.z * wv[u][i].z + a.w * wv[u][i].w;
          }
        }
      }
    }

    // one batched butterfly over all 80 accumulators
#pragma unroll
    for (int s = 32; s >= 1; s >>= 1) {
#pragma unroll
      for (int r = 0; r < 4; ++r)
#pragma unroll
        for (int jj = 0; jj < 20; ++jj)
          acc[r][jj] += __shfl_xor(acc[r][jj], s, 64);
    }

    if (lane == 0) {
#pragma unroll
      for (int jj = 0; jj < 20; ++jj) {
        const int j = j0w + jj;
        const float bias = (j < 24) ? b_t2c[j] : (j < 32) ? b_code[j - 24]
                         : (j < 56) ? b_ctx[j - 32] : b_ctx[j - 56];
#pragma unroll
        for (int r = 0; r < 4; ++r) s_proj[r][j] = acc[r][jj] + bias;
      }
    }
    __syncthreads();

    if (tid < 16) {
      const int r = tid >> 2, g = tid & 3;
      const int st[5] = {0, 24, 32, 56, 80};
      float ss = 0.f;
      for (int k = st[g]; k < st[g + 1]; ++k) ss += s_proj[r][k] * s_proj[r][k];
      s_inv2[r][g] = 1.f / fmaxf(sqrtf(ss), 1e-8f);
    }
    __syncthreads();
    for (int base = tid; base < 320; base += 256) {
      const int r = base / 80, j = base % 80;
      const int g = (j < 24) ? 0 : (j < 32) ? 1 : (j < 56) ? 2 : 3;
      xall[(size_t)(row0 + r) * 80 + j] = s_proj[r][j] * s_inv2[r][g];
    }
  } else if (bid < 512 + N_CTRY) {
    // ---------------- country-table projection path ----------------
    float* pchat = ws + OFF_PCHAT;
    const int b = bid - 512;

    float4 in4[3];
#pragma unroll
    for (int i = 0; i < 3; ++i)
      in4[i] = ((const float4*)(ctab + (size_t)b * BERT))[lane + 64 * i];

    float acc6[6];
#pragma unroll
    for (int jj = 0; jj < 6; ++jj) acc6[jj] = 0.f;
#pragma unroll
    for (int jj = 0; jj < 6; ++jj) {
      const int j = w * 6 + jj;
      const float4* wr = (const float4*)(W_cet + (size_t)j * BERT);
#pragma unroll
      for (int i = 0; i < 3; ++i) {
        float4 wv = wr[lane + 64 * i];
        acc6[jj] += in4[i].x * wv.x + in4[i].y * wv.y + in4[i].z * wv.z + in4[i].w * wv.w;
      }
    }
#pragma unroll
    for (int s = 32; s >= 1; s >>= 1)
#pragma unroll
      for (int jj = 0; jj < 6; ++jj) acc6[jj] += __shfl_xor(acc6[jj], s, 64);

    if (lane == 0) {
#pragma unroll
      for (int jj = 0; jj < 6; ++jj) {
        const int j = w * 6 + jj;
        s_proj[0][j] = acc6[jj] + b_cet[j];
      }
    }
    __syncthreads();
    if (tid == 0) {
      float ss = 0.f;
      for (int k = 0; k < 24; ++k) ss += s_proj[0][k] * s_proj[0][k];
      s_inv2[0][0] = 1.f / fmaxf(sqrtf(ss), 1e-8f);
    }
    __syncthreads();
    if (tid < 24) pchat[b * 24 + tid] = s_proj[0][tid] * s_inv2[0][0];
  } else {
    // ---------------- code-embedding normalization path ----------------
    float* codehat = ws + OFF_CODEHAT;
    const int idx = (bid - 512 - N_CTRY) * 256 + tid;
    if (idx < N_CODES) {
      float v[8];
      float ss = 0.f;
#pragma unroll
      for (int k = 0; k < 8; ++k) { v[k] = code_emb[idx * 8 + k]; ss += v[k] * v[k]; }
      const float inv = 1.f / fmaxf(sqrtf(ss), 1e-8f);
#pragma unroll
      for (int k = 0; k < 8; ++k) codehat[idx * 8 + k] = v[k] * inv;
    }
  }
}

// ---------------------------------------------------------------------------
// Kernel 3: per-(b,c) classify. 256 threads = 4 waves = 4 rows; lane = class.
// C = 64 == wave size, so softmax is one wave butterfly.
// ---------------------------------------------------------------------------
__global__ __launch_bounds__(256) void k3_classify(
    const int* __restrict__ fcodes, const int* __restrict__ ccodes,
    const float* __restrict__ gaz,
    const float* __restrict__ W_mix1, const float* __restrict__ b_mix1,
    const float* __restrict__ W_mix2, const float* __restrict__ b_mix2,
    const float* __restrict__ W_last, const float* __restrict__ b_last,
    const float* __restrict__ ws, float* __restrict__ out) {
  const float* pchat   = ws + OFF_PCHAT;
  const float* codehat = ws + OFF_CODEHAT;
  const float* xall    = ws + OFF_XALL;
  const int tid = threadIdx.x;
  const int w = tid >> 6, lane = tid & 63;
  const int row = __builtin_amdgcn_readfirstlane(blockIdx.x * 4 + w);
  const float* xv = xall + (size_t)row * 80;

  const int cidx = ccodes[row * CC + lane];
  const int fidx = fcodes[row * CC + lane];

  float cc[24];
  {
    const float4* p4 = (const float4*)(pchat + cidx * 24);
#pragma unroll
    for (int i = 0; i < 6; ++i) {
      float4 v = p4[i];
      cc[4 * i + 0] = v.x; cc[4 * i + 1] = v.y; cc[4 * i + 2] = v.z; cc[4 * i + 3] = v.w;
    }
  }
  float cd[8];
  {
    const float4* q4 = (const float4*)(codehat + fidx * 8);
#pragma unroll
    for (int i = 0; i < 2; ++i) {
      float4 v = q4[i];
      cd[4 * i + 0] = v.x; cd[4 * i + 1] = v.y; cd[4 * i + 2] = v.z; cd[4 * i + 3] = v.w;
    }
  }

  float sc = 0.f, so = 0.f, sd = 0.f, sq = 0.f;
#pragma unroll
  for (int k = 0; k < 24; ++k) {
    sc += xv[k] * cc[k];
    so += xv[32 + k] * cc[k];
    sd += xv[56 + k] * cc[k];
  }
#pragma unroll
  for (int k = 0; k < 8; ++k) sq += xv[24 + k] * cd[k];

  float f[13];
  f[0] = sc; f[1] = sq; f[2] = so; f[3] = sd;
  {
    const float* g = gaz + (size_t)(row * CC + lane) * 9;
#pragma unroll
    for (int i = 0; i < 9; ++i) f[4 + i] = g[i];
  }

  float h1[24];
#pragma unroll
  for (int j = 0; j < 24; ++j) {
    float a = b_mix1[j];
#pragma unroll
    for (int i = 0; i < 13; ++i) a += W_mix1[j * 13 + i] * f[i];
    h1[j] = 1.f / (1.f + __expf(-a));
  }
  float h2[24];
#pragma unroll
  for (int j = 0; j < 24; ++j) {
    float a = b_mix2[j];
#pragma unroll
    for (int i = 0; i < 24; ++i) a += W_mix2[j * 24 + i] * h1[i];
    h2[j] = 1.f / (1.f + __expf(-a));
  }
  float last = b_last[0];
#pragma unroll
  for (int k = 0; k < 24; ++k) last += W_last[k] * h2[k];

  // softmax across the 64 lanes (classes)
  float m = last;
#pragma unroll
  for (int s = 32; s >= 1; s >>= 1) m = fmaxf(m, __shfl_xor(m, s, 64));
  const float e = __expf(last - m);
  float ssum = e;
#pragma unroll
  for (int s = 32; s >= 1; s >>= 1) ssum += __shfl_xor(ssum, s, 64);
  out[row * CC + lane] = e / ssum;
}

// ---------------------------------------------------------------------------
extern "C" void kernel_launch(void* const* d_in, const int* in_sizes, int n_in,
                              void* d_out, int out_size, void* d_ws, size_t ws_size,
                              hipStream_t stream) {
  const float* place   = (const float*)d_in[0];
  const float* other   = (const float*)d_in[1];
  const float* doc     = (const float*)d_in[2];
  const int*   fcodes  = (const int*)d_in[3];
  const int*   ccodes  = (const int*)d_in[4];
  const float* gaz     = (const float*)d_in[5];
  const float* code_emb= (const float*)d_in[6];
  const float* ctab    = (const float*)d_in[7];
  const float* W_cet   = (const float*)d_in[8];
  const float* b_cet   = (const float*)d_in[9];
  const float* W_t2c   = (const float*)d_in[10];
  const float* b_t2c   = (const float*)d_in[11];
  const float* W_ctx   = (const float*)d_in[12];
  const float* b_ctx   = (const float*)d_in[13];
  const float* W_code  = (const float*)d_in[14];
  const float* b_code  = (const float*)d_in[15];
  const float* W_mix1  = (const float*)d_in[16];
  const float* b_mix1  = (const float*)d_in[17];
  const float* W_mix2  = (const float*)d_in[18];
  const float* b_mix2  = (const float*)d_in[19];
  const float* W_last  = (const float*)d_in[20];
  const float* b_last  = (const float*)d_in[21];
  float* ws  = (float*)d_ws;
  float* out = (float*)d_out;

  // A: 512 projection blocks + 250 country blocks + 3 code-norm blocks
  kA_fused<<<512 + N_CTRY + 3, 256, 0, stream>>>(
      place, other, doc, W_t2c, b_t2c, W_code, b_code, W_ctx, b_ctx,
      ctab, W_cet, b_cet, code_emb, ws);
  // B: 2048 rows / 4 rows per block
  k3_classify<<<BB / 4, 256, 0, stream>>>(fcodes, ccodes, gaz, W_mix1, b_mix1,
                                          W_mix2, b_mix2, W_last, b_last, ws, out);
}